// Round 8
// baseline (137.420 us; speedup 1.0000x reference)
//
#include <hip/hip_runtime.h>

#define B_ 8
#define K_ 4096
#define C_ 128
#define KN 16

typedef __attribute__((ext_vector_type(8))) short bf16x8;
typedef __attribute__((ext_vector_type(4))) float f32x4;

__device__ __forceinline__ unsigned short f2bf(float f) {
  unsigned u = __float_as_uint(f);
  unsigned r = (u + 0x7FFFu + ((u >> 16) & 1u)) >> 16;
  return (unsigned short)r;
}
__device__ __forceinline__ float bfl(unsigned u) {
  return __uint_as_float(u << 16);
}
__device__ __forceinline__ float bfh(unsigned u) {
  return __uint_as_float(u & 0xffff0000u);
}

__device__ __forceinline__ float dist_exact(float4 q, float4 c) {
  float dot = __fadd_rn(__fadd_rn(__fmul_rn(q.x, c.x), __fmul_rn(q.y, c.y)),
                        __fmul_rn(q.z, c.z));
  return __fadd_rn(__fadd_rn(q.w, c.w), __fmul_rn(-2.0f, dot));
}
// rank-equivalent screen value: e = c.w/2 - q.c  (d = 2e + q.w, monotone)
__device__ __forceinline__ float escr(float4 q, float4 c, float ch) {
  return fmaf(-q.x, c.x, fmaf(-q.y, c.y, fmaf(-q.z, c.z, ch)));
}

// ---------------------------------------------------------------------------
// Kernel 1 (fused pre): lnpos | pack | wcatT by block range
// WT col layout: [0:128]=S_a, [128:256]=S_f, [256:512]= interleaved
// (256+2c = N_a[c], 257+2c = N_f[c]) so attn reads one dwordx2 per lane.
// ---------------------------------------------------------------------------
__global__ __launch_bounds__(256) void k_pre(
    const float* __restrict__ x, const float* __restrict__ pos,
    const float* __restrict__ gamma, const float* __restrict__ beta,
    const float* __restrict__ Wa1, const float* __restrict__ Wf1,
    const float* __restrict__ coords, unsigned short* __restrict__ A,
    unsigned short* __restrict__ WT, float4* __restrict__ cc4) {
  int blk = blockIdx.x;
  if (blk < 8192) {
    int wave = threadIdx.x >> 6;
    int lane = threadIdx.x & 63;
    size_t row = (size_t)blk * 4 + wave;
    const float2* xr = (const float2*)(x + row * C_);
    const float2* pr = (const float2*)(pos + row * C_);
    float2 a = xr[lane];
    float s = a.x + a.y;
#pragma unroll
    for (int o = 1; o < 64; o <<= 1) s += __shfl_xor(s, o);
    float mu = s * (1.0f / 128.0f);
    float dx = a.x - mu, dy = a.y - mu;
    float v = dx * dx + dy * dy;
#pragma unroll
    for (int o = 1; o < 64; o <<= 1) v += __shfl_xor(v, o);
    float rstd = rsqrtf(v * (1.0f / 128.0f) + 1e-5f);
    float2 gm = ((const float2*)gamma)[lane];
    float2 bt = ((const float2*)beta)[lane];
    float2 pp = pr[lane];
    float o0 = dx * rstd * gm.x + bt.x + pp.x;
    float o1 = dy * rstd * gm.y + bt.y + pp.y;
    ushort2 o = make_ushort2(f2bf(o0), f2bf(o1));
    *(ushort2*)(A + row * C_ + 2 * lane) = o;
  } else if (blk < 8320) {
    int i = (blk - 8192) * 256 + threadIdx.x;
    float px = coords[i * 3], py = coords[i * 3 + 1], pz = coords[i * 3 + 2];
    float w = __fadd_rn(__fadd_rn(__fmul_rn(px, px), __fmul_rn(py, py)),
                        __fmul_rn(pz, pz));
    cc4[i] = make_float4(px, py, pz, w);
  } else {
    int i = (blk - 8320) * 256 + threadIdx.x;  // 0..65535
    int q = i >> 7;
    int r = i & 127;
    float v;
    if (q < 128)
      v = Wa1[r * 128 + q];
    else if (q < 256)
      v = Wf1[r * 128 + (q - 128)] - Wf1[(128 + r) * 128 + (q - 128)];
    else {
      int c = (q - 256) >> 1;
      if (((q - 256) & 1) == 0)
        v = Wa1[(128 + r) * 128 + c];
      else
        v = Wf1[(128 + r) * 128 + c];
    }
    WT[i] = f2bf(v);
  }
}

// ---------------------------------------------------------------------------
// Kernel 2: exact kNN, wave per 8 queries; e-space screen, atomic compaction,
// exact-bit recompute + lex sort in pass C (selected set == reference).
// Self is gathered in pass B and excluded by index in pass C.
// ---------------------------------------------------------------------------
__global__ __launch_bounds__(256) void k_knn8(const float4* __restrict__ cc4,
                                              int* __restrict__ idx) {
  __shared__ unsigned cbuf[4][8][64];
  __shared__ unsigned scnt[4][8];
  int wave = threadIdx.x >> 6, lane = threadIdx.x & 63;
  int gw = blockIdx.x * 4 + wave;  // 0..4095
  int b = gw >> 9;                 // 512 waves per batch
  int qbase = (gw & 511) * 8;
  const float4* cb = cc4 + (size_t)b * K_;
  if (lane < 8) scnt[wave][lane] = 0u;
  __asm__ volatile("s_waitcnt lgkmcnt(0)" ::: "memory");
  float4 Q[8];
#pragma unroll
  for (int qq = 0; qq < 8; ++qq) Q[qq] = cb[qbase + qq];

  // ---- pass A: per-lane min of e over its candidate slice (self included;
  // self pollutes exactly one lane's min per query -> 17th-smallest bound) ----
  float mn[8];
#pragma unroll
  for (int qq = 0; qq < 8; ++qq) mn[qq] = 1e30f;
#pragma unroll 4
  for (int it = 0; it < 64; ++it) {
    float4 c = cb[(it << 6) + lane];
    float ch = c.w * 0.5f;
#pragma unroll
    for (int qq = 0; qq < 8; ++qq) mn[qq] = fminf(mn[qq], escr(Q[qq], c, ch));
  }
  // ---- bound = 17th smallest lane-min + slack (covers self + fp error) ----
  float ub[8];
#pragma unroll
  for (int qq = 0; qq < 8; ++qq) {
    float v = mn[qq];
#pragma unroll
    for (int k = 2; k <= 64; k <<= 1) {
#pragma unroll
      for (int jj = k >> 1; jj >= 1; jj >>= 1) {
        float o = __shfl_xor(v, jj);
        bool amHigh = (lane & jj) != 0;
        bool up = (lane & k) != 0;
        bool gt = v > o;
        bool take = (amHigh ? !gt : gt) ^ up;
        v = take ? o : v;
      }
    }
    ub[qq] = __shfl(v, 16) + 5e-4f;
  }

  // ---- pass B: gather indices with e <= ub via LDS atomic compaction ----
#pragma unroll 2
  for (int it = 0; it < 64; ++it) {
    int j = (it << 6) + lane;
    float4 c = cb[j];
    float ch = c.w * 0.5f;
#pragma unroll
    for (int qq = 0; qq < 8; ++qq) {
      float e = escr(Q[qq], c, ch);
      if (e <= ub[qq]) {
        unsigned pos = atomicAdd(&scnt[wave][qq], 1u);
        if (pos < 64u) cbuf[wave][qq][pos] = (unsigned)j;
      }
    }
  }
  __asm__ volatile("s_waitcnt lgkmcnt(0)" ::: "memory");

  // ---- pass C: exact dist recompute, self-exclude, lex sort, take 16 ----
#pragma unroll
  for (int qq = 0; qq < 8; ++qq) {
    unsigned m = scnt[wave][qq];
    m = m < 64u ? m : 64u;
    bool valid = lane < (int)m;
    unsigned ji = valid ? cbuf[wave][qq][lane] : 0u;
    if (valid && ji == (unsigned)(qbase + qq)) valid = false;
    float4 c = cb[ji];
    float dC = valid ? dist_exact(Q[qq], c) : 1e30f;
    int iC = valid ? (int)ji : 0x7fffffff;
#pragma unroll
    for (int k = 2; k <= 64; k <<= 1) {
#pragma unroll
      for (int jj = k >> 1; jj >= 1; jj >>= 1) {
        float od = __shfl_xor(dC, jj);
        int oi = __shfl_xor(iC, jj);
        bool amHigh = (lane & jj) != 0;
        bool up = (lane & k) != 0;
        bool gt = (dC > od) || (dC == od && iC > oi);
        bool take = (amHigh ? !gt : gt) ^ up;
        dC = take ? od : dC;
        iC = take ? oi : iC;
      }
    }
    if (lane < KN)
      idx[((size_t)b * K_ + (qbase + qq)) * KN + lane] = iC;
  }
}

// ---------------------------------------------------------------------------
// Kernel 3: MFMA GEMM  SN_bf16[32768,512] = A_bf16[32768,128] @ WcatT^T
// 128x128 tile, 4 waves. batch = blockIdx&7 -> batch b L2-resident on XCD b.
// ---------------------------------------------------------------------------
__global__ __launch_bounds__(256) void k_gemm_mfma(
    const unsigned short* __restrict__ A, const unsigned short* __restrict__ BT,
    unsigned short* __restrict__ SN) {
  __shared__ char lB[32768];
  int bb = blockIdx.x & 7;
  int rest = blockIdx.x >> 3;
  int mbl = rest >> 2, nb = rest & 3;
  int m0 = bb * 4096 + mbl * 128, n0 = nb * 128;
  int t = threadIdx.x;
  {
    const char* src = (const char*)(BT + (size_t)n0 * 128);
#pragma unroll
    for (int i = 0; i < 8; ++i) {
      int byte = (t + i * 256) * 16;
      int n = byte >> 8;
      int sb = byte ^ ((n & 7) << 4);
      *(float4*)(lB + sb) = *(const float4*)(src + byte);
    }
  }
  __syncthreads();
  int wave = t >> 6, lane = t & 63;
  int wr = wave >> 1, wc = wave & 1;
  int lm = lane & 15, lk = lane >> 4;
  f32x4 z = {0.f, 0.f, 0.f, 0.f};
  f32x4 acc00 = z, acc01 = z, acc02 = z, acc03 = z;
  f32x4 acc10 = z, acc11 = z, acc12 = z, acc13 = z;
  f32x4 acc20 = z, acc21 = z, acc22 = z, acc23 = z;
  f32x4 acc30 = z, acc31 = z, acc32 = z, acc33 = z;
  const char* abase =
      (const char*)A + (size_t)(m0 + wr * 64 + lm) * 256 + lk * 16;
#pragma unroll
  for (int ks = 0; ks < 4; ++ks) {
    bf16x8 af[4], bfr[4];
#pragma unroll
    for (int mt = 0; mt < 4; ++mt)
      af[mt] = *(const bf16x8*)(abase + (size_t)mt * 4096 + ks * 64);
#pragma unroll
    for (int nt = 0; nt < 4; ++nt) {
      int n_local = wc * 64 + nt * 16 + lm;
      int byte = n_local * 256 + ks * 64 + lk * 16;
      byte ^= (n_local & 7) << 4;
      bfr[nt] = *(const bf16x8*)(lB + byte);
    }
    acc00 = __builtin_amdgcn_mfma_f32_16x16x32_bf16(af[0], bfr[0], acc00, 0, 0, 0);
    acc01 = __builtin_amdgcn_mfma_f32_16x16x32_bf16(af[0], bfr[1], acc01, 0, 0, 0);
    acc02 = __builtin_amdgcn_mfma_f32_16x16x32_bf16(af[0], bfr[2], acc02, 0, 0, 0);
    acc03 = __builtin_amdgcn_mfma_f32_16x16x32_bf16(af[0], bfr[3], acc03, 0, 0, 0);
    acc10 = __builtin_amdgcn_mfma_f32_16x16x32_bf16(af[1], bfr[0], acc10, 0, 0, 0);
    acc11 = __builtin_amdgcn_mfma_f32_16x16x32_bf16(af[1], bfr[1], acc11, 0, 0, 0);
    acc12 = __builtin_amdgcn_mfma_f32_16x16x32_bf16(af[1], bfr[2], acc12, 0, 0, 0);
    acc13 = __builtin_amdgcn_mfma_f32_16x16x32_bf16(af[1], bfr[3], acc13, 0, 0, 0);
    acc20 = __builtin_amdgcn_mfma_f32_16x16x32_bf16(af[2], bfr[0], acc20, 0, 0, 0);
    acc21 = __builtin_amdgcn_mfma_f32_16x16x32_bf16(af[2], bfr[1], acc21, 0, 0, 0);
    acc22 = __builtin_amdgcn_mfma_f32_16x16x32_bf16(af[2], bfr[2], acc22, 0, 0, 0);
    acc23 = __builtin_amdgcn_mfma_f32_16x16x32_bf16(af[2], bfr[3], acc23, 0, 0, 0);
    acc30 = __builtin_amdgcn_mfma_f32_16x16x32_bf16(af[3], bfr[0], acc30, 0, 0, 0);
    acc31 = __builtin_amdgcn_mfma_f32_16x16x32_bf16(af[3], bfr[1], acc31, 0, 0, 0);
    acc32 = __builtin_amdgcn_mfma_f32_16x16x32_bf16(af[3], bfr[2], acc32, 0, 0, 0);
    acc33 = __builtin_amdgcn_mfma_f32_16x16x32_bf16(af[3], bfr[3], acc33, 0, 0, 0);
  }
  f32x4 accs[4][4] = {{acc00, acc01, acc02, acc03},
                      {acc10, acc11, acc12, acc13},
                      {acc20, acc21, acc22, acc23},
                      {acc30, acc31, acc32, acc33}};
#pragma unroll
  for (int mt = 0; mt < 4; ++mt) {
#pragma unroll
    for (int nt = 0; nt < 4; ++nt) {
#pragma unroll
      for (int r = 0; r < 4; ++r) {
        int row = m0 + wr * 64 + mt * 16 + lk * 4 + r;
        int col = n0 + wc * 64 + nt * 16 + lm;
        SN[(size_t)row * 512 + col] = f2bf(accs[mt][nt][r]);
      }
    }
  }
}

// ---------------------------------------------------------------------------
// Kernel 4: attention aggregate, wave per point, XCD-local batches.
// Neighbor block interleaved: one dwordx2 per lane = (Na[2l],Nf[2l],Na[2l+1],Nf[2l+1])
// ---------------------------------------------------------------------------
__global__ __launch_bounds__(256) void k_attn(
    const unsigned short* __restrict__ SN, const int* __restrict__ idx,
    const float* __restrict__ b_a1, const float* __restrict__ b_f1,
    const float* __restrict__ W_a2, const float* __restrict__ b_a2,
    float* __restrict__ out) {
  int wave = threadIdx.x >> 6, lane = threadIdx.x & 63;
  int b = blockIdx.x & 7;
  int w = blockIdx.x >> 3;  // 0..1023
  size_t g = (size_t)b * K_ + w * 4 + wave;
  const unsigned* sr = (const unsigned*)(SN + g * 512);
  unsigned usa = sr[lane], usf = sr[64 + lane];
  float s_a0 = bfl(usa), s_a1 = bfh(usa);
  float s_f0 = bfl(usf), s_f1 = bfh(usf);
  float2 ba = ((const float2*)b_a1)[lane];
  float2 bf = ((const float2*)b_f1)[lane];
  float2 w2 = ((const float2*)W_a2)[lane];
  float ba2 = b_a2[0];
  int nv = 0;
  if (lane < 16) nv = idx[g * 16 + lane];
  float lg[16], t0a[16], t1a[16];
#pragma unroll
  for (int j = 0; j < 16; ++j) {
    int n = __shfl(nv, j);
    const unsigned short* nr = SN + ((size_t)b * K_ + n) * 512;
    uint2 u2 = *(const uint2*)(nr + 256 + 4 * lane);
    float h0 = s_a0 + bfl(u2.x) + ba.x;
    h0 = h0 >= 0.0f ? h0 : 0.2f * h0;
    float h1 = s_a1 + bfl(u2.y) + ba.y;
    h1 = h1 >= 0.0f ? h1 : 0.2f * h1;
    float t0 = s_f0 + bfh(u2.x) + bf.x;
    t0 = t0 >= 0.0f ? t0 : 0.2f * t0;
    float t1 = s_f1 + bfh(u2.y) + bf.y;
    t1 = t1 >= 0.0f ? t1 : 0.2f * t1;
    float pl = h0 * w2.x + h1 * w2.y;
#pragma unroll
    for (int o = 1; o < 64; o <<= 1) pl += __shfl_xor(pl, o);
    lg[j] = pl + ba2;
    t0a[j] = t0;
    t1a[j] = t1;
  }
  float m = lg[0];
#pragma unroll
  for (int j = 1; j < 16; ++j) m = fmaxf(m, lg[j]);
  float s = 0.0f;
  float e[16];
#pragma unroll
  for (int j = 0; j < 16; ++j) {
    e[j] = expf(lg[j] - m);
    s += e[j];
  }
  float inv = 1.0f / s;
  float o0 = 0.0f, o1 = 0.0f;
#pragma unroll
  for (int j = 0; j < 16; ++j) {
    float a = e[j] * inv;
    o0 += a * t0a[j];
    o1 += a * t1a[j];
  }
  *(float2*)(out + g * 128 + 2 * lane) = make_float2(o0, o1);
}

// ---------------------------------------------------------------------------
extern "C" void kernel_launch(void* const* d_in, const int* in_sizes, int n_in,
                              void* d_out, int out_size, void* d_ws,
                              size_t ws_size, hipStream_t stream) {
  const float* x = (const float*)d_in[0];
  const float* pos = (const float*)d_in[1];
  const float* coords = (const float*)d_in[2];
  const float* gamma = (const float*)d_in[3];
  const float* beta = (const float*)d_in[4];
  const float* Wa1 = (const float*)d_in[5];
  const float* ba1 = (const float*)d_in[6];
  const float* Wa2 = (const float*)d_in[7];
  const float* ba2 = (const float*)d_in[8];
  const float* Wf1 = (const float*)d_in[9];
  const float* bf1 = (const float*)d_in[10];
  float* out = (float*)d_out;

  char* ws = (char*)d_ws;
  unsigned short* A = (unsigned short*)ws;                                // 8MB
  unsigned short* SN = (unsigned short*)(ws + (size_t)16 * 1024 * 1024);  // 32MB
  unsigned short* WT = (unsigned short*)(ws + (size_t)80 * 1024 * 1024);  // 128KB
  int* idx = (int*)(ws + (size_t)80 * 1024 * 1024 + 512 * 1024);          // 2MB
  float4* cc4 = (float4*)(ws + (size_t)80 * 1024 * 1024 + 2560 * 1024);   // 512KB

  k_pre<<<8576, 256, 0, stream>>>(x, pos, gamma, beta, Wa1, Wf1, coords, A, WT,
                                  cc4);
  k_knn8<<<1024, 256, 0, stream>>>(cc4, idx);
  k_gemm_mfma<<<1024, 256, 0, stream>>>(A, WT, SN);
  k_attn<<<8192, 256, 0, stream>>>(SN, idx, ba1, bf1, Wa2, ba2, out);
}

// Round 9
// 110.662 us; speedup vs baseline: 1.2418x; 1.2418x over previous
//
#include <hip/hip_runtime.h>

#define B_ 8
#define K_ 4096
#define C_ 128
#define KN 16

typedef __attribute__((ext_vector_type(8))) short bf16x8;
typedef __attribute__((ext_vector_type(4))) float f32x4;

__device__ __forceinline__ unsigned short f2bf(float f) {
  unsigned u = __float_as_uint(f);
  unsigned r = (u + 0x7FFFu + ((u >> 16) & 1u)) >> 16;
  return (unsigned short)r;
}
__device__ __forceinline__ float bf2f(unsigned short s) {
  return __uint_as_float(((unsigned)s) << 16);
}

__device__ __forceinline__ float dist_exact(float4 q, float4 c) {
  float dot = __fadd_rn(__fadd_rn(__fmul_rn(q.x, c.x), __fmul_rn(q.y, c.y)),
                        __fmul_rn(q.z, c.z));
  return __fadd_rn(__fadd_rn(q.w, c.w), __fmul_rn(-2.0f, dot));
}
// rank-equivalent screen value: e = c.w/2 - q.c  (d = 2e + q.w, monotone)
__device__ __forceinline__ float escr(float4 q, float4 c, float ch) {
  return fmaf(-q.x, c.x, fmaf(-q.y, c.y, fmaf(-q.z, c.z, ch)));
}

// ---------------------------------------------------------------------------
// Kernel 1 (fused pre): lnpos | pack | wcatT by block range
// WT col layout: [0:128]=S_a, [128:256]=S_f, [256:512] interleaved
// (256+2c = N_a[c], 257+2c = N_f[c]).
// ---------------------------------------------------------------------------
__global__ __launch_bounds__(256) void k_pre(
    const float* __restrict__ x, const float* __restrict__ pos,
    const float* __restrict__ gamma, const float* __restrict__ beta,
    const float* __restrict__ Wa1, const float* __restrict__ Wf1,
    const float* __restrict__ coords, unsigned short* __restrict__ A,
    unsigned short* __restrict__ WT, float4* __restrict__ cc4) {
  int blk = blockIdx.x;
  if (blk < 8192) {
    int wave = threadIdx.x >> 6;
    int lane = threadIdx.x & 63;
    size_t row = (size_t)blk * 4 + wave;
    const float2* xr = (const float2*)(x + row * C_);
    const float2* pr = (const float2*)(pos + row * C_);
    float2 a = xr[lane];
    float s = a.x + a.y;
#pragma unroll
    for (int o = 1; o < 64; o <<= 1) s += __shfl_xor(s, o);
    float mu = s * (1.0f / 128.0f);
    float dx = a.x - mu, dy = a.y - mu;
    float v = dx * dx + dy * dy;
#pragma unroll
    for (int o = 1; o < 64; o <<= 1) v += __shfl_xor(v, o);
    float rstd = rsqrtf(v * (1.0f / 128.0f) + 1e-5f);
    float2 gm = ((const float2*)gamma)[lane];
    float2 bt = ((const float2*)beta)[lane];
    float2 pp = pr[lane];
    float o0 = dx * rstd * gm.x + bt.x + pp.x;
    float o1 = dy * rstd * gm.y + bt.y + pp.y;
    ushort2 o = make_ushort2(f2bf(o0), f2bf(o1));
    *(ushort2*)(A + row * C_ + 2 * lane) = o;
  } else if (blk < 8320) {
    int i = (blk - 8192) * 256 + threadIdx.x;
    float px = coords[i * 3], py = coords[i * 3 + 1], pz = coords[i * 3 + 2];
    float w = __fadd_rn(__fadd_rn(__fmul_rn(px, px), __fmul_rn(py, py)),
                        __fmul_rn(pz, pz));
    cc4[i] = make_float4(px, py, pz, w);
  } else {
    int i = (blk - 8320) * 256 + threadIdx.x;  // 0..65535
    int q = i >> 7;
    int r = i & 127;
    float v;
    if (q < 128)
      v = Wa1[r * 128 + q];
    else if (q < 256)
      v = Wf1[r * 128 + (q - 128)] - Wf1[(128 + r) * 128 + (q - 128)];
    else {
      int c = (q - 256) >> 1;
      if (((q - 256) & 1) == 0)
        v = Wa1[(128 + r) * 128 + c];
      else
        v = Wf1[(128 + r) * 128 + c];
    }
    WT[i] = f2bf(v);
  }
}

// ---------------------------------------------------------------------------
// Kernel 2: exact kNN, wave per 4 queries. Pass A screens 3/4 of candidates
// for the bound (order-stat argument keeps it valid); pass B gathers by
// fast e over all; pass C recomputes exact bits, excludes self, lex-sorts.
// ---------------------------------------------------------------------------
__global__ __launch_bounds__(256) void k_knn(const float4* __restrict__ cc4,
                                             int* __restrict__ idx) {
  __shared__ unsigned cbuf[4][4][64];
  __shared__ unsigned scnt[4][4];
  int wave = threadIdx.x >> 6, lane = threadIdx.x & 63;
  int gw = blockIdx.x * 4 + wave;  // 0..8191
  int b = gw >> 10;
  int qbase = (gw & 1023) * 4;
  const float4* cb = cc4 + (size_t)b * K_;
  if (lane < 4) scnt[wave][lane] = 0u;
  __asm__ volatile("s_waitcnt lgkmcnt(0)" ::: "memory");
  float4 Q[4];
#pragma unroll
  for (int qq = 0; qq < 4; ++qq) Q[qq] = cb[qbase + qq];

  // ---- pass A: per-lane min of e over 48-candidate slice (3072 total) ----
  float m0 = 1e30f, m1 = 1e30f, m2 = 1e30f, m3 = 1e30f;
#pragma unroll 4
  for (int it = 0; it < 48; ++it) {
    float4 c = cb[(it << 6) + lane];
    float ch = c.w * 0.5f;
    m0 = fminf(m0, escr(Q[0], c, ch));
    m1 = fminf(m1, escr(Q[1], c, ch));
    m2 = fminf(m2, escr(Q[2], c, ch));
    m3 = fminf(m3, escr(Q[3], c, ch));
  }
  // ---- bound = 17th smallest lane-min + slack ----
  float ub[4];
  float mv[4] = {m0, m1, m2, m3};
#pragma unroll
  for (int qq = 0; qq < 4; ++qq) {
    float v = mv[qq];
#pragma unroll
    for (int k = 2; k <= 64; k <<= 1) {
#pragma unroll
      for (int jj = k >> 1; jj >= 1; jj >>= 1) {
        float o = __shfl_xor(v, jj);
        bool amHigh = (lane & jj) != 0;
        bool up = (lane & k) != 0;
        bool gt = v > o;
        bool take = (amHigh ? !gt : gt) ^ up;
        v = take ? o : v;
      }
    }
    ub[qq] = __shfl(v, 16) + 5e-4f;
  }

  // ---- pass B: gather indices with e <= ub (self gathered, excluded in C) --
#pragma unroll 2
  for (int it = 0; it < 64; ++it) {
    int j = (it << 6) + lane;
    float4 c = cb[j];
    float ch = c.w * 0.5f;
#pragma unroll
    for (int qq = 0; qq < 4; ++qq) {
      float e = escr(Q[qq], c, ch);
      if (e <= ub[qq]) {
        unsigned pos = atomicAdd(&scnt[wave][qq], 1u);
        if (pos < 64u) cbuf[wave][qq][pos] = (unsigned)j;
      }
    }
  }
  __asm__ volatile("s_waitcnt lgkmcnt(0)" ::: "memory");

  // ---- pass C: exact recompute, self-exclude, lex sort, take 16 ----
#pragma unroll
  for (int qq = 0; qq < 4; ++qq) {
    unsigned m = scnt[wave][qq];
    m = m < 64u ? m : 64u;
    bool valid = lane < (int)m;
    unsigned ji = valid ? cbuf[wave][qq][lane] : 0u;
    if (valid && ji == (unsigned)(qbase + qq)) valid = false;
    float4 c = cb[ji];
    float dC = valid ? dist_exact(Q[qq], c) : 1e30f;
    int iC = valid ? (int)ji : 0x7fffffff;
#pragma unroll
    for (int k = 2; k <= 64; k <<= 1) {
#pragma unroll
      for (int jj = k >> 1; jj >= 1; jj >>= 1) {
        float od = __shfl_xor(dC, jj);
        int oi = __shfl_xor(iC, jj);
        bool amHigh = (lane & jj) != 0;
        bool up = (lane & k) != 0;
        bool gt = (dC > od) || (dC == od && iC > oi);
        bool take = (amHigh ? !gt : gt) ^ up;
        dC = take ? od : dC;
        iC = take ? oi : iC;
      }
    }
    if (lane < KN)
      idx[((size_t)b * K_ + (qbase + qq)) * KN + lane] = iC;
  }
}

// ---------------------------------------------------------------------------
// Kernel 3: MFMA GEMM  SN_bf16[32768,512] = A_bf16[32768,128] @ WcatT^T
// 128x128 tile, 4 waves. batch = blockIdx&7 -> batch b L2-resident on XCD b.
// ---------------------------------------------------------------------------
__global__ __launch_bounds__(256) void k_gemm_mfma(
    const unsigned short* __restrict__ A, const unsigned short* __restrict__ BT,
    unsigned short* __restrict__ SN) {
  __shared__ char lB[32768];
  int bb = blockIdx.x & 7;
  int rest = blockIdx.x >> 3;
  int mbl = rest >> 2, nb = rest & 3;
  int m0 = bb * 4096 + mbl * 128, n0 = nb * 128;
  int t = threadIdx.x;
  {
    const char* src = (const char*)(BT + (size_t)n0 * 128);
#pragma unroll
    for (int i = 0; i < 8; ++i) {
      int byte = (t + i * 256) * 16;
      int n = byte >> 8;
      int sb = byte ^ ((n & 7) << 4);
      *(float4*)(lB + sb) = *(const float4*)(src + byte);
    }
  }
  __syncthreads();
  int wave = t >> 6, lane = t & 63;
  int wr = wave >> 1, wc = wave & 1;
  int lm = lane & 15, lk = lane >> 4;
  f32x4 z = {0.f, 0.f, 0.f, 0.f};
  f32x4 acc00 = z, acc01 = z, acc02 = z, acc03 = z;
  f32x4 acc10 = z, acc11 = z, acc12 = z, acc13 = z;
  f32x4 acc20 = z, acc21 = z, acc22 = z, acc23 = z;
  f32x4 acc30 = z, acc31 = z, acc32 = z, acc33 = z;
  const char* abase =
      (const char*)A + (size_t)(m0 + wr * 64 + lm) * 256 + lk * 16;
#pragma unroll
  for (int ks = 0; ks < 4; ++ks) {
    bf16x8 af[4], bfr[4];
#pragma unroll
    for (int mt = 0; mt < 4; ++mt)
      af[mt] = *(const bf16x8*)(abase + (size_t)mt * 4096 + ks * 64);
#pragma unroll
    for (int nt = 0; nt < 4; ++nt) {
      int n_local = wc * 64 + nt * 16 + lm;
      int byte = n_local * 256 + ks * 64 + lk * 16;
      byte ^= (n_local & 7) << 4;
      bfr[nt] = *(const bf16x8*)(lB + byte);
    }
    acc00 = __builtin_amdgcn_mfma_f32_16x16x32_bf16(af[0], bfr[0], acc00, 0, 0, 0);
    acc01 = __builtin_amdgcn_mfma_f32_16x16x32_bf16(af[0], bfr[1], acc01, 0, 0, 0);
    acc02 = __builtin_amdgcn_mfma_f32_16x16x32_bf16(af[0], bfr[2], acc02, 0, 0, 0);
    acc03 = __builtin_amdgcn_mfma_f32_16x16x32_bf16(af[0], bfr[3], acc03, 0, 0, 0);
    acc10 = __builtin_amdgcn_mfma_f32_16x16x32_bf16(af[1], bfr[0], acc10, 0, 0, 0);
    acc11 = __builtin_amdgcn_mfma_f32_16x16x32_bf16(af[1], bfr[1], acc11, 0, 0, 0);
    acc12 = __builtin_amdgcn_mfma_f32_16x16x32_bf16(af[1], bfr[2], acc12, 0, 0, 0);
    acc13 = __builtin_amdgcn_mfma_f32_16x16x32_bf16(af[1], bfr[3], acc13, 0, 0, 0);
    acc20 = __builtin_amdgcn_mfma_f32_16x16x32_bf16(af[2], bfr[0], acc20, 0, 0, 0);
    acc21 = __builtin_amdgcn_mfma_f32_16x16x32_bf16(af[2], bfr[1], acc21, 0, 0, 0);
    acc22 = __builtin_amdgcn_mfma_f32_16x16x32_bf16(af[2], bfr[2], acc22, 0, 0, 0);
    acc23 = __builtin_amdgcn_mfma_f32_16x16x32_bf16(af[2], bfr[3], acc23, 0, 0, 0);
    acc30 = __builtin_amdgcn_mfma_f32_16x16x32_bf16(af[3], bfr[0], acc30, 0, 0, 0);
    acc31 = __builtin_amdgcn_mfma_f32_16x16x32_bf16(af[3], bfr[1], acc31, 0, 0, 0);
    acc32 = __builtin_amdgcn_mfma_f32_16x16x32_bf16(af[3], bfr[2], acc32, 0, 0, 0);
    acc33 = __builtin_amdgcn_mfma_f32_16x16x32_bf16(af[3], bfr[3], acc33, 0, 0, 0);
  }
  f32x4 accs[4][4] = {{acc00, acc01, acc02, acc03},
                      {acc10, acc11, acc12, acc13},
                      {acc20, acc21, acc22, acc23},
                      {acc30, acc31, acc32, acc33}};
#pragma unroll
  for (int mt = 0; mt < 4; ++mt) {
#pragma unroll
    for (int nt = 0; nt < 4; ++nt) {
#pragma unroll
      for (int r = 0; r < 4; ++r) {
        int row = m0 + wr * 64 + mt * 16 + lk * 4 + r;
        int col = n0 + wc * 64 + nt * 16 + lm;
        SN[(size_t)row * 512 + col] = f2bf(accs[mt][nt][r]);
      }
    }
  }
}

// ---------------------------------------------------------------------------
// Kernel 4: attention aggregate. Wave per point; lane (g=lane>>4, r=lane&15)
// handles channels [8r,8r+8) of neighbors {g,4+g,8+g,12+g}. Logit reduction
// = 4 stages over 16 lanes; output reduced over g at the end.
// ---------------------------------------------------------------------------
__global__ __launch_bounds__(256) void k_attn(
    const unsigned short* __restrict__ SN, const int* __restrict__ idx,
    const float* __restrict__ b_a1, const float* __restrict__ b_f1,
    const float* __restrict__ W_a2, const float* __restrict__ b_a2,
    float* __restrict__ out) {
  int wave = threadIdx.x >> 6, lane = threadIdx.x & 63;
  int g = lane >> 4, r = lane & 15;
  int b = blockIdx.x & 7;
  int w = blockIdx.x >> 3;  // 0..1023
  size_t gpt = (size_t)b * K_ + w * 4 + wave;
  const unsigned short* sr = SN + gpt * 512;
  bf16x8 sa8 = *(const bf16x8*)(sr + 8 * r);
  bf16x8 sf8 = *(const bf16x8*)(sr + 128 + 8 * r);
  float4 bav0 = *(const float4*)(b_a1 + 8 * r);
  float4 bav1 = *(const float4*)(b_a1 + 8 * r + 4);
  float4 bfv0 = *(const float4*)(b_f1 + 8 * r);
  float4 bfv1 = *(const float4*)(b_f1 + 8 * r + 4);
  float4 w2v0 = *(const float4*)(W_a2 + 8 * r);
  float4 w2v1 = *(const float4*)(W_a2 + 8 * r + 4);
  float sab[8], sfb[8], w2v[8];
  {
    float bav[8] = {bav0.x, bav0.y, bav0.z, bav0.w, bav1.x, bav1.y, bav1.z, bav1.w};
    float bfv[8] = {bfv0.x, bfv0.y, bfv0.z, bfv0.w, bfv1.x, bfv1.y, bfv1.z, bfv1.w};
    float wv[8] = {w2v0.x, w2v0.y, w2v0.z, w2v0.w, w2v1.x, w2v1.y, w2v1.z, w2v1.w};
#pragma unroll
    for (int i = 0; i < 8; ++i) {
      sab[i] = bf2f((unsigned short)sa8[i]) + bav[i];
      sfb[i] = bf2f((unsigned short)sf8[i]) + bfv[i];
      w2v[i] = wv[i];
    }
  }
  float ba2v = b_a2[0];
  int nv = 0;
  if (lane < 16) nv = idx[gpt * 16 + lane];
  float lgl[4];
  float tsv[4][8];
#pragma unroll
  for (int round = 0; round < 4; ++round) {
    int n = __shfl(nv, round * 4 + g);
    const unsigned short* nr =
        SN + ((size_t)b * K_ + n) * 512 + 256 + 16 * r;
    bf16x8 u0 = *(const bf16x8*)(nr);
    bf16x8 u1 = *(const bf16x8*)(nr + 8);
    float dot = 0.0f;
#pragma unroll
    for (int i = 0; i < 4; ++i) {
      float h = sab[i] + bf2f((unsigned short)u0[2 * i]);
      h = h >= 0.0f ? h : 0.2f * h;
      float tv = sfb[i] + bf2f((unsigned short)u0[2 * i + 1]);
      tv = tv >= 0.0f ? tv : 0.2f * tv;
      dot = fmaf(h, w2v[i], dot);
      tsv[round][i] = tv;
    }
#pragma unroll
    for (int i = 0; i < 4; ++i) {
      float h = sab[4 + i] + bf2f((unsigned short)u1[2 * i]);
      h = h >= 0.0f ? h : 0.2f * h;
      float tv = sfb[4 + i] + bf2f((unsigned short)u1[2 * i + 1]);
      tv = tv >= 0.0f ? tv : 0.2f * tv;
      dot = fmaf(h, w2v[4 + i], dot);
      tsv[round][4 + i] = tv;
    }
#pragma unroll
    for (int o = 1; o < 16; o <<= 1) dot += __shfl_xor(dot, o);
    lgl[round] = dot + ba2v;
  }
  float mx = fmaxf(fmaxf(lgl[0], lgl[1]), fmaxf(lgl[2], lgl[3]));
  mx = fmaxf(mx, __shfl_xor(mx, 16));
  mx = fmaxf(mx, __shfl_xor(mx, 32));
  float e[4];
  float s = 0.0f;
#pragma unroll
  for (int round = 0; round < 4; ++round) {
    e[round] = expf(lgl[round] - mx);
    s += e[round];
  }
  s += __shfl_xor(s, 16);
  s += __shfl_xor(s, 32);
  float inv = 1.0f / s;
  float o8[8] = {0, 0, 0, 0, 0, 0, 0, 0};
#pragma unroll
  for (int round = 0; round < 4; ++round) {
    float a = e[round] * inv;
#pragma unroll
    for (int i = 0; i < 8; ++i) o8[i] = fmaf(a, tsv[round][i], o8[i]);
  }
#pragma unroll
  for (int i = 0; i < 8; ++i) {
    o8[i] += __shfl_xor(o8[i], 16);
    o8[i] += __shfl_xor(o8[i], 32);
  }
  if (g == 0) {
    float* op = out + gpt * 128 + 8 * r;
    *(float4*)op = make_float4(o8[0], o8[1], o8[2], o8[3]);
    *(float4*)(op + 4) = make_float4(o8[4], o8[5], o8[6], o8[7]);
  }
}

// ---------------------------------------------------------------------------
extern "C" void kernel_launch(void* const* d_in, const int* in_sizes, int n_in,
                              void* d_out, int out_size, void* d_ws,
                              size_t ws_size, hipStream_t stream) {
  const float* x = (const float*)d_in[0];
  const float* pos = (const float*)d_in[1];
  const float* coords = (const float*)d_in[2];
  const float* gamma = (const float*)d_in[3];
  const float* beta = (const float*)d_in[4];
  const float* Wa1 = (const float*)d_in[5];
  const float* ba1 = (const float*)d_in[6];
  const float* Wa2 = (const float*)d_in[7];
  const float* ba2 = (const float*)d_in[8];
  const float* Wf1 = (const float*)d_in[9];
  const float* bf1 = (const float*)d_in[10];
  float* out = (float*)d_out;

  char* ws = (char*)d_ws;
  unsigned short* A = (unsigned short*)ws;                                // 8MB
  unsigned short* SN = (unsigned short*)(ws + (size_t)16 * 1024 * 1024);  // 32MB
  unsigned short* WT = (unsigned short*)(ws + (size_t)80 * 1024 * 1024);  // 128KB
  int* idx = (int*)(ws + (size_t)80 * 1024 * 1024 + 512 * 1024);          // 2MB
  float4* cc4 = (float4*)(ws + (size_t)80 * 1024 * 1024 + 2560 * 1024);   // 512KB

  k_pre<<<8576, 256, 0, stream>>>(x, pos, gamma, beta, Wa1, Wf1, coords, A, WT,
                                  cc4);
  k_knn<<<2048, 256, 0, stream>>>(cc4, idx);
  k_gemm_mfma<<<1024, 256, 0, stream>>>(A, WT, SN);
  k_attn<<<8192, 256, 0, stream>>>(SN, idx, ba1, bf1, Wa2, ba2, out);
}